// Round 12
// baseline (38.775 us; speedup 1.0000x reference)
//
#include <hip/hip_runtime.h>

// P = dW/dF for W(F) = 8*tr(C) + 10*J^2 - 56*log(J) + 0.2*(I4^2 + I5^2) - 44
// C = F^T F, J = det F, G = diag(4, .5, .5), I4 = tr(C G), I5 = tr(cof(C) G)
// Analytic gradient:
//   P = 16 F + [20 J^2 - 56 + 0.8 I5^2] F^-T + 0.8 I4 * F G - 0.8 I5 * F^-T G cofC
// with F^-T = cof(F)/J, cofC = cof(C).
//
// R11: R10 but stores emitted via inline asm with sc1+nt (system-scope +
//   non-temporal). Theory: builtin nt alone didn't change L3 residency
//   (R10 null); full memory-side-cache bypass on gfx950 may need sc1 too.
//   Goal: output stream stops evicting the input from L3 -> replay reads
//   become L3 hits -> HBM traffic ~= writes only.
//   Tripwires: WRITE_SIZE > 150 MB (sc1 defeats write-combining) or
//   dur >= 38 us (L3 policy not controllable) -> declare roofline.

typedef float f2 __attribute__((ext_vector_type(2)));

#define TPB 256
#define SAMPLES_PER_TILE 512
#define F2_PER_TILE (SAMPLES_PER_TILE * 9 / 2)   // 2304 f2 = 18 KB
#define NBLOCKS 1024

__global__ __launch_bounds__(TPB) void pk1_grad_kernel(
    const f2* __restrict__ Fin, f2* __restrict__ Pout, int total2, int ntiles)
{
    __shared__ f2 ldsX[F2_PER_TILE];   // staged input tile
    __shared__ f2 ldsY[F2_PER_TILE];   // staged output tile
    const int t = threadIdx.x;

    // ---- prologue: load first tile into prefetch registers ----
    f2 pre[9];
    {
        const int base2 = blockIdx.x * F2_PER_TILE;
#pragma unroll
        for (int q = 0; q < 9; ++q) {
            int g = base2 + q * TPB + t;
            if (g < total2) pre[q] = Fin[g];
            else { pre[q].x = 1.0f; pre[q].y = 1.0f; }   // benign pad
        }
    }

    for (int tile = blockIdx.x; tile < ntiles; tile += NBLOCKS) {
        const int base2 = tile * F2_PER_TILE;

        // ---- stage current tile regs -> LDS X ----
#pragma unroll
        for (int q = 0; q < 9; ++q) ldsX[q * TPB + t] = pre[q];
        __syncthreads();   // B1: X ready

        // ---- issue prefetch for tile k+1 (in flight during compute/store) ----
        const int ntile = tile + NBLOCKS;
        if (ntile < ntiles) {                 // block-uniform branch
            const int nbase2 = ntile * F2_PER_TILE;
#pragma unroll
            for (int q = 0; q < 9; ++q) {
                int g = nbase2 + q * TPB + t;
                if (g < total2) pre[q] = Fin[g];
                else { pre[q].x = 1.0f; pre[q].y = 1.0f; }
            }
        }

        // ---- compute 2 samples from X (stride-9 f2 reads: conflict-free) ----
        float buf[18];
#pragma unroll
        for (int q = 0; q < 9; ++q) {
            f2 v = ldsX[t * 9 + q];
            buf[2 * q]     = v.x;
            buf[2 * q + 1] = v.y;
        }

#pragma unroll
        for (int s = 0; s < 2; ++s) {
            float f[9];
#pragma unroll
            for (int k = 0; k < 9; ++k) f[k] = buf[s * 9 + k];

            // cof(F): F^-T = cof(F)/J
            float c00 = f[4]*f[8] - f[5]*f[7];
            float c01 = f[5]*f[6] - f[3]*f[8];
            float c02 = f[3]*f[7] - f[4]*f[6];
            float c10 = f[2]*f[7] - f[1]*f[8];
            float c11 = f[0]*f[8] - f[2]*f[6];
            float c12 = f[1]*f[6] - f[0]*f[7];
            float c20 = f[1]*f[5] - f[2]*f[4];
            float c21 = f[2]*f[3] - f[0]*f[5];
            float c22 = f[0]*f[4] - f[1]*f[3];
            float J    = f[0]*c00 + f[1]*c01 + f[2]*c02;
            float invJ = 1.0f / J;

            // C = F^T F (symmetric)
            float C00 = f[0]*f[0] + f[3]*f[3] + f[6]*f[6];
            float C11 = f[1]*f[1] + f[4]*f[4] + f[7]*f[7];
            float C22 = f[2]*f[2] + f[5]*f[5] + f[8]*f[8];
            float C01 = f[0]*f[1] + f[3]*f[4] + f[6]*f[7];
            float C02 = f[0]*f[2] + f[3]*f[5] + f[6]*f[8];
            float C12 = f[1]*f[2] + f[4]*f[5] + f[7]*f[8];

            float I4 = 4.0f*C00 + 0.5f*(C11 + C22);

            // cof(C) (symmetric)
            float K00 = C11*C22 - C12*C12;
            float K11 = C00*C22 - C02*C02;
            float K22 = C00*C11 - C01*C01;
            float K01 = C02*C12 - C01*C22;
            float K02 = C01*C12 - C02*C11;
            float K12 = C01*C02 - C00*C12;

            float I5 = 4.0f*K00 + 0.5f*(K11 + K22);

            float J2    = J * J;
            float alpha = (20.0f*J2 - 56.0f + 0.8f*I5*I5) * invJ;
            float beta  = 0.8f * I4;
            float gamma = -0.8f * I5 * invJ;

            float cf[3][3] = {{c00,c01,c02},{c10,c11,c12},{c20,c21,c22}};
            float K[3][3]  = {{K00,K01,K02},{K01,K11,K12},{K02,K12,K22}};
            const float gv[3] = {4.0f, 0.5f, 0.5f};

#pragma unroll
            for (int i = 0; i < 3; ++i) {
                float a0 = cf[i][0] * 4.0f;
                float a1 = cf[i][1] * 0.5f;
                float a2 = cf[i][2] * 0.5f;
#pragma unroll
                for (int j = 0; j < 3; ++j) {
                    float M = a0 * K[0][j] + a1 * K[1][j] + a2 * K[2][j];
                    buf[s * 9 + 3 * i + j] =
                          (16.0f + beta * gv[j]) * f[3 * i + j]
                        + alpha * cf[i][j]
                        + gamma * M;
                }
            }
        }

        // ---- results -> LDS Y (thread-private stride-9 slots) ----
#pragma unroll
        for (int q = 0; q < 9; ++q) {
            f2 v;
            v.x = buf[2 * q];
            v.y = buf[2 * q + 1];
            ldsY[t * 9 + q] = v;
        }
        __syncthreads();   // B2: Y ready (and all X-reads of this tile done)

        // ---- coalesced sc1+nt stores: Y -> global (stream past L3) ----
#pragma unroll
        for (int q = 0; q < 9; ++q) {
            int g = base2 + q * TPB + t;
            if (g < total2) {
                f2 v = ldsY[q * TPB + t];
                f2* addr = &Pout[g];
                asm volatile("global_store_dwordx2 %0, %1, off sc1 nt"
                             :: "v"(addr), "v"(v) : "memory");
            }
        }
        // next iteration overwrites X (disjoint from Y) then hits B1 -- safe.
    }
}

extern "C" void kernel_launch(void* const* d_in, const int* in_sizes, int n_in,
                              void* d_out, int out_size, void* d_ws, size_t ws_size,
                              hipStream_t stream) {
    const f2* F = (const f2*)d_in[0];
    f2* P = (f2*)d_out;
    int total2 = in_sizes[0] / 2;                          // 13,500,000 f2
    int ntiles = (total2 + F2_PER_TILE - 1) / F2_PER_TILE; // 5860
    pk1_grad_kernel<<<NBLOCKS, TPB, 0, stream>>>(F, P, total2, ntiles);
}